// Round 1
// baseline (2298.800 us; speedup 1.0000x reference)
//
#include <hip/hip_runtime.h>
#include <cstddef>

// Problem constants
constexpr int HP  = 128 * 128;          // half-res pixels per channel
constexpr long long S = 8LL * 64 * HP;  // elements per (8,64,128,128) buffer

// ---------------------------------------------------------------- DWT (Haar)
__global__ __launch_bounds__(256) void k_dwt(const float* __restrict__ x,
                                             float* __restrict__ ll, float* __restrict__ lh,
                                             float* __restrict__ hl, float* __restrict__ hh) {
    long long idx = (long long)blockIdx.x * 256 + threadIdx.x;
    if (idx >= S) return;
    int j  = (int)(idx & 127);
    int i  = (int)((idx >> 7) & 127);
    long long bc = idx >> 14;
    const float* xp = x + bc * 256 * 256;
    float2 top = *(const float2*)(xp + (2 * i) * 256 + 2 * j);
    float2 bot = *(const float2*)(xp + (2 * i + 1) * 256 + 2 * j);
    float a = top.x, b = top.y, c = bot.x, d = bot.y;
    ll[idx] = (a + b + c + d) * 0.5f;
    lh[idx] = (a - b + c - d) * 0.5f;
    hl[idx] = (a + b - c - d) * 0.5f;
    hh[idx] = (a - b - c + d) * 0.5f;
}

// ------------------------------------------- grouped 3x3 conv (+ReLU), tiled
// in : (8,64,128,128) standalone tensor (one group's input)
// w  : (64 oc, 64 ic, 3, 3) flat, group base
// out: element (b, oc) lands at out[((b*out_ctot + oc)*HP) + p]
//      (caller offsets `out` to the group's channel-0)
__global__ __launch_bounds__(256) void k_conv3x3_relu(const float* __restrict__ in,
                                                      const float* __restrict__ w,
                                                      float* __restrict__ out,
                                                      int out_ctot) {
    __shared__ float wl[8 * 576];     // 8 oc x (64 ic x 9)
    __shared__ float tile[18][20];    // 16x16 tile + halo, padded stride
    int tx = threadIdx.x, ty = threadIdx.y;
    int tid = ty * 16 + tx;
    int tileid = blockIdx.x;          // 0..63 (8x8 tiles)
    int occ = blockIdx.y;             // oc chunk of 8
    int b = blockIdx.z;
    int ty0 = (tileid >> 3) * 16, tx0 = (tileid & 7) * 16;

    for (int idx = tid; idx < 8 * 576; idx += 256)
        wl[idx] = w[occ * 8 * 576 + idx];

    const float* inb = in + (size_t)b * 64 * HP;
    float acc[8] = {0, 0, 0, 0, 0, 0, 0, 0};

    for (int ic = 0; ic < 64; ++ic) {
        __syncthreads();
        for (int idx = tid; idx < 18 * 18; idx += 256) {
            int ry = idx / 18, rx = idx % 18;
            int gy = ty0 + ry - 1, gx = tx0 + rx - 1;
            float v = 0.0f;
            if (gy >= 0 && gy < 128 && gx >= 0 && gx < 128)
                v = inb[ic * HP + gy * 128 + gx];
            tile[ry][rx] = v;
        }
        __syncthreads();
        float tv[9];
#pragma unroll
        for (int ky = 0; ky < 3; ++ky)
#pragma unroll
            for (int kx = 0; kx < 3; ++kx)
                tv[ky * 3 + kx] = tile[ty + ky][tx + kx];
#pragma unroll
        for (int o = 0; o < 8; ++o) {
#pragma unroll
            for (int k = 0; k < 9; ++k)
                acc[o] += tv[k] * wl[o * 576 + ic * 9 + k];
        }
    }
    int gy = ty0 + ty, gx = tx0 + tx;
#pragma unroll
    for (int o = 0; o < 8; ++o) {
        int oc = occ * 8 + o;
        out[((size_t)b * out_ctot + oc) * HP + gy * 128 + gx] = fmaxf(acc[o], 0.0f);
    }
}

// ----------------------------------------------------- 1x1 conv, 64 out ch
// in: (8, IC, 128,128); w laid out (OC=64, IC); out: (8,64,128,128)
template <int IC, bool RELU>
__global__ __launch_bounds__(256) void k_conv1x1(const float* __restrict__ in,
                                                 const float* __restrict__ w,
                                                 float* __restrict__ out) {
    __shared__ float wl[IC * 16];  // [ic][o] transposed for vector ds_read
    int tid = threadIdx.x;
    int occ = blockIdx.y, b = blockIdx.z;
    for (int idx = tid; idx < IC * 16; idx += 256) {
        int o = idx & 15, ic = idx >> 4;
        wl[idx] = w[(occ * 16 + o) * IC + ic];
    }
    __syncthreads();
    int p = blockIdx.x * 256 + tid;
    const float* inp = in + (size_t)b * IC * HP + p;
    float acc[16] = {};
    for (int ic = 0; ic < IC; ++ic) {
        float xv = inp[(size_t)ic * HP];
#pragma unroll
        for (int o = 0; o < 16; ++o) acc[o] += xv * wl[ic * 16 + o];
    }
    float* op = out + ((size_t)b * 64 + occ * 16) * HP + p;
#pragma unroll
    for (int o = 0; o < 16; ++o) op[o * HP] = RELU ? fmaxf(acc[o], 0.0f) : acc[o];
}

// ------------------------------- depthwise 3x3 (V slice) fused with v*(1+filt)
__global__ __launch_bounds__(256) void k_dwconv_v(const float* __restrict__ t,
                                                  const float* __restrict__ wdw,  // base at row 128: (64,9)
                                                  const float* __restrict__ filt,
                                                  float* __restrict__ v) {
    long long idx = (long long)blockIdx.x * 256 + threadIdx.x;
    if (idx >= S) return;
    int j = (int)(idx & 127);
    int i = (int)((idx >> 7) & 127);
    int c = (int)((idx >> 14) & 63);
    long long bc = idx >> 14;
    const float* tp = t + bc * HP;
    const float* wp = wdw + c * 9;
    float acc = 0.0f;
#pragma unroll
    for (int ky = 0; ky < 3; ++ky) {
        int y = i + ky - 1;
        if (y < 0 || y >= 128) continue;
#pragma unroll
        for (int kx = 0; kx < 3; ++kx) {
            int x = j + kx - 1;
            if (x < 0 || x >= 128) continue;
            acc += tp[y * 128 + x] * wp[ky * 3 + kx];
        }
    }
    float f = filt[idx];
    v[idx] = acc * (1.0f + f);  // v_inp*filt + v_inp
}

// ---------------------------------------------------- window attention (8x8)
// q from rolled ll (shift -4), v from unshifted v; out written with roll +4.
__global__ __launch_bounds__(256) void k_attn(const float* __restrict__ ll,
                                              const float* __restrict__ v,
                                              const float* __restrict__ table,
                                              const float* __restrict__ temp,
                                              float* __restrict__ outbuf) {
    __shared__ float qs[64][64];   // [c][n]
    __shared__ float vs[64][64];
    __shared__ float inv[4][64];
    __shared__ float tb[225 * 4];
    int blk = blockIdx.x;
    int wj = blk & 15, wi = (blk >> 4) & 15, b = blk >> 8;
    int tid = threadIdx.x;

    for (int idx = tid; idx < 900; idx += 256) tb[idx] = table[idx];
    for (int idx = tid; idx < 4096; idx += 256) {
        int c = idx >> 6, n = idx & 63;
        int i = n >> 3, j = n & 7;
        int qy = (wi * 8 + i + 4) & 127, qx = (wj * 8 + j + 4) & 127;
        int vy = wi * 8 + i, vx = wj * 8 + j;
        size_t cb = ((size_t)b * 64 + c) * HP;
        qs[c][n] = ll[cb + qy * 128 + qx];
        vs[c][n] = v[cb + vy * 128 + vx];
    }
    __syncthreads();

    int h = tid >> 6, n = tid & 63;
    float q[16];
    float ss = 0.0f;
#pragma unroll
    for (int d = 0; d < 16; ++d) {
        q[d] = qs[h * 16 + d][n];
        ss += q[d] * q[d];
    }
    float invn = 1.0f / fmaxf(sqrtf(ss), 1e-12f);
    inv[h][n] = invn;
    __syncthreads();

    int i1 = n >> 3, j1 = n & 7;
    float tscale = temp[h];
    float p[64];
    float mx = -1e30f;
#pragma unroll
    for (int m = 0; m < 64; ++m) {
        float s = 0.0f;
#pragma unroll
        for (int d = 0; d < 16; ++d) s += q[d] * qs[h * 16 + d][m];
        s = s * invn * inv[h][m];
        int i2 = m >> 3, j2 = m & 7;
        s += tb[((i1 - i2 + 7) * 15 + (j1 - j2 + 7)) * 4 + h];
        s *= tscale;
        p[m] = s;
        mx = fmaxf(mx, s);
    }
    float sum = 0.0f;
#pragma unroll
    for (int m = 0; m < 64; ++m) {
        p[m] = __expf(p[m] - mx);
        sum += p[m];
    }
    float rs = 1.0f / sum;
    float acc[16] = {};
#pragma unroll
    for (int m = 0; m < 64; ++m) {
        float pm = p[m] * rs;
#pragma unroll
        for (int d = 0; d < 16; ++d) acc[d] += pm * vs[h * 16 + d][m];
    }
    int oy = (wi * 8 + i1 + 4) & 127, ox = (wj * 8 + j1 + 4) & 127;
#pragma unroll
    for (int d = 0; d < 16; ++d)
        outbuf[((size_t)b * 64 + h * 16 + d) * HP + oy * 128 + ox] = acc[d];
}

// ---------------------------------------------------------------- IDWT (Haar)
__global__ __launch_bounds__(256) void k_idwt(const float* __restrict__ ll, const float* __restrict__ lh,
                                              const float* __restrict__ hl, const float* __restrict__ hh,
                                              float* __restrict__ out) {
    long long idx = (long long)blockIdx.x * 256 + threadIdx.x;
    if (idx >= S) return;
    int j = (int)(idx & 127);
    int i = (int)((idx >> 7) & 127);
    long long bc = idx >> 14;
    float L = ll[idx], A = lh[idx], B = hl[idx], D = hh[idx];
    float a = (L + A + B + D) * 0.5f;
    float b = (L - A + B - D) * 0.5f;
    float c = (L + A - B - D) * 0.5f;
    float d = (L - A - B + D) * 0.5f;
    float* op = out + bc * 256 * 256;
    *(float2*)(op + (2 * i) * 256 + 2 * j) = make_float2(a, b);
    *(float2*)(op + (2 * i + 1) * 256 + 2 * j) = make_float2(c, d);
}

extern "C" void kernel_launch(void* const* d_in, const int* in_sizes, int n_in,
                              void* d_out, int out_size, void* d_ws, size_t ws_size,
                              hipStream_t stream) {
    const float* x        = (const float*)d_in[0];
    const float* temp     = (const float*)d_in[1];
    const float* table    = (const float*)d_in[2];
    const float* w_high1  = (const float*)d_in[3];  // (128,64,3,3)
    const float* w_high2  = (const float*)d_in[4];  // (64,128,1,1)
    const float* w_highout= (const float*)d_in[5];  // (192,64,3,3)
    const float* w_qkv    = (const float*)d_in[6];  // (192,64,1,1)
    const float* w_dwconv = (const float*)d_in[7];  // (192,1,3,3)
    const float* w_proj   = (const float*)d_in[8];  // (64,64,1,1)
    float* out = (float*)d_out;

    float* ws = (float*)d_ws;
    // Buffer slots (each S elements), lifetime-reused:
    float* bll   = ws + 0 * S;   // ll            (live k1..k6)
    float* blh   = ws + 1 * S;   // lh            (live k1..k8)
    float* bhl   = ws + 2 * S;   // hl
    float* bhh   = ws + 3 * S;   // hh
    float* bfv   = ws + 4 * S;   // filt -> v (in-place)
    float* bproj = ws + 5 * S;   // proj output
    float* bF    = ws + 6 * S;   // filt1 ch 0..63  -> lh2
    float* bG    = ws + 7 * S;   // filt1 ch 64..127-> hl2
    float* bH    = ws + 8 * S;   // t -> attnout -> hh2

    const int nblk = (int)(S / 256);
    dim3 b256(256);

    // 1. DWT
    k_dwt<<<nblk, b256, 0, stream>>>(x, bll, blh, bhl, bhh);

    // 2. filt = relu(conv3x3 grouped g=2 on [lh,hl]) -> filt1 in (bF,bG) as (8,128,HP)
    dim3 cgrid(64, 8, 8), cblk(16, 16);
    k_conv3x3_relu<<<cgrid, cblk, 0, stream>>>(blh, w_high1,            bF, 128);            // oc 0..63
    k_conv3x3_relu<<<cgrid, cblk, 0, stream>>>(bhl, w_high1 + 64 * 576, bF + 64 * HP, 128);  // oc 64..127

    // 3. filt = relu(1x1 128->64)
    dim3 g1(64, 4, 8);
    k_conv1x1<128, true><<<g1, b256, 0, stream>>>(bF, w_high2, bfv);

    // 4. t = 1x1 conv of ll with V-rows of w_qkv (channels 128..191)
    k_conv1x1<64, false><<<g1, b256, 0, stream>>>(bll, w_qkv + 128 * 64, bH);

    // 5. v = dwconv3x3(t) * (1 + filt), in-place over filt buffer
    k_dwconv_v<<<nblk, b256, 0, stream>>>(bH, w_dwconv + 128 * 9, bfv, bfv);

    // 6. window attention -> attnout (bH, t consumed)
    k_attn<<<2048, b256, 0, stream>>>(bll, bfv, table, temp, bH);

    // 7. proj 1x1
    k_conv1x1<64, false><<<g1, b256, 0, stream>>>(bH, w_proj, bproj);

    // 8. high-frequency output branch: 3 grouped conv3x3 + relu
    k_conv3x3_relu<<<cgrid, cblk, 0, stream>>>(blh, w_highout,             bF, 64);  // lh2
    k_conv3x3_relu<<<cgrid, cblk, 0, stream>>>(bhl, w_highout + 64 * 576,  bG, 64);  // hl2
    k_conv3x3_relu<<<cgrid, cblk, 0, stream>>>(bhh, w_highout + 128 * 576, bH, 64);  // hh2

    // 9. IDWT -> out
    k_idwt<<<nblk, b256, 0, stream>>>(bproj, bF, bG, bH, out);
}

// Round 2
// 656.536 us; speedup vs baseline: 3.5014x; 3.5014x over previous
//
#include <hip/hip_runtime.h>
#include <cstddef>

// Problem constants
constexpr int HP  = 128 * 128;          // half-res pixels per channel
constexpr long long S = 8LL * 64 * HP;  // elements per (8,64,128,128) buffer

using short8 = __attribute__((ext_vector_type(8))) short;
using f32x4  = __attribute__((ext_vector_type(4))) float;

__device__ __forceinline__ unsigned short f2bf(float x) {
    union { float f; unsigned int u; } v{x};
    unsigned int r = v.u + 0x7FFFu + ((v.u >> 16) & 1u);  // RNE
    return (unsigned short)(r >> 16);
}

// ---------------------------------------------------------------- DWT (Haar)
__global__ __launch_bounds__(256) void k_dwt(const float* __restrict__ x,
                                             float* __restrict__ ll, float* __restrict__ lh,
                                             float* __restrict__ hl, float* __restrict__ hh) {
    long long idx = (long long)blockIdx.x * 256 + threadIdx.x;
    if (idx >= S) return;
    int j  = (int)(idx & 127);
    int i  = (int)((idx >> 7) & 127);
    long long bc = idx >> 14;
    const float* xp = x + bc * 256 * 256;
    float2 top = *(const float2*)(xp + (2 * i) * 256 + 2 * j);
    float2 bot = *(const float2*)(xp + (2 * i + 1) * 256 + 2 * j);
    float a = top.x, b = top.y, c = bot.x, d = bot.y;
    ll[idx] = (a + b + c + d) * 0.5f;
    lh[idx] = (a - b + c - d) * 0.5f;
    hl[idx] = (a + b - c - d) * 0.5f;
    hh[idx] = (a - b - c + d) * 0.5f;
}

// ---------------------------------------- planar fp32 -> NHWC bf16 transpose
// in: (8,64,HP) fp32 ; out: (8,HP,64) bf16
__global__ __launch_bounds__(256) void k_to_nhwc(const float* __restrict__ in,
                                                 unsigned short* __restrict__ out) {
    __shared__ float t[64][65];
    int b = blockIdx.y;
    int p0 = blockIdx.x * 64;
    int tid = threadIdx.x;
    const float* ib = in + (size_t)b * 64 * HP;
    {
        int p = tid & 63, c4 = tid >> 6;
#pragma unroll
        for (int k = 0; k < 16; ++k) {
            int c = c4 * 16 + k;
            t[c][p] = ib[(size_t)c * HP + p0 + p];
        }
    }
    __syncthreads();
    {
        int c = tid & 63, pq = tid >> 6;
        unsigned short* ob = out + ((size_t)b * HP + p0) * 64;
#pragma unroll
        for (int k = 0; k < 16; ++k) {
            int p = pq * 16 + k;
            ob[(size_t)p * 64 + c] = f2bf(t[c][p]);
        }
    }
}

// ------------------------------- weight reorder (oc,ic,3,3) fp32 -> [oc][s*64+ic] bf16
__global__ __launch_bounds__(256) void k_wreorder(const float* __restrict__ w,
                                                  unsigned short* __restrict__ wr, int total) {
    int idx = blockIdx.x * 256 + threadIdx.x;
    if (idx >= total) return;
    int oc = idx / 576, rem = idx - oc * 576;
    int s = rem >> 6, ic = rem & 63;
    wr[idx] = f2bf(w[(oc * 64 + ic) * 9 + s]);
}

// -------------------------- grouped 3x3 conv (+ReLU) via implicit-GEMM MFMA
// in : NHWC bf16 (8, HP, 64) for this group's input channels
// wr : reordered bf16 weights [64 oc][576] (k = s*64+ic)
// out: planar fp32, element (b,oc,p) at out[((b*out_ctot+oc)*HP)+p]
#define ISTR 72   // per-pixel LDS stride in bf16 (64 data + 8 pad)
__global__ __launch_bounds__(256, 2) void k_conv3x3_mfma(
        const unsigned short* __restrict__ in,
        const unsigned short* __restrict__ wr,
        float* __restrict__ out, int out_ctot) {
    __shared__ __align__(16) unsigned short lin[324 * ISTR];  // 18x18 px halo tile
    __shared__ __align__(16) unsigned short lw[64 * ISTR];    // per-s weights 64oc x 64ic

    int tid = threadIdx.x;
    int b = blockIdx.y;
    int ty0 = (blockIdx.x >> 3) * 16, tx0 = (blockIdx.x & 7) * 16;

    // ---- stage input tile (once): 324 pixel-rows x 128B each
    const unsigned short* inb = in + (size_t)b * HP * 64;
    for (int idx = tid; idx < 324 * 8; idx += 256) {
        int pr = idx >> 3, l8 = idx & 7;
        int py = pr / 18, px = pr - py * 18;
        int gy = ty0 + py - 1, gx = tx0 + px - 1;
        uint4 v = make_uint4(0, 0, 0, 0);
        if (gy >= 0 && gy < 128 && gx >= 0 && gx < 128)
            v = *(const uint4*)(inb + ((size_t)(gy * 128 + gx)) * 64 + l8 * 8);
        *(uint4*)&lin[pr * ISTR + l8 * 8] = v;
    }

    int wv = tid >> 6;
    int lane = tid & 63;
    int n16 = lane & 15, quad = lane >> 4;

    f32x4 acc[4][4];
#pragma unroll
    for (int mt = 0; mt < 4; ++mt)
#pragma unroll
        for (int nt = 0; nt < 4; ++nt) acc[mt][nt] = (f32x4){0.f, 0.f, 0.f, 0.f};

    for (int s = 0; s < 9; ++s) {
        __syncthreads();
        // stage this s's 64x64 weight block
        for (int idx = tid; idx < 512; idx += 256) {
            int oc = idx >> 3, l8 = idx & 7;
            *(uint4*)&lw[oc * ISTR + l8 * 8] =
                *(const uint4*)(wr + oc * 576 + s * 64 + l8 * 8);
        }
        __syncthreads();
        int sy = s / 3, sx = s - sy * 3;
#pragma unroll
        for (int half = 0; half < 2; ++half) {
            int ic0 = half * 32 + quad * 8;
            short8 a[4], bf[4];
#pragma unroll
            for (int mt = 0; mt < 4; ++mt)
                a[mt] = *(const short8*)&lw[(mt * 16 + n16) * ISTR + ic0];
#pragma unroll
            for (int nt = 0; nt < 4; ++nt) {
                int py = 4 * wv + nt + sy;
                int px = n16 + sx;
                bf[nt] = *(const short8*)&lin[(py * 18 + px) * ISTR + ic0];
            }
#pragma unroll
            for (int mt = 0; mt < 4; ++mt)
#pragma unroll
                for (int nt = 0; nt < 4; ++nt)
                    acc[mt][nt] = __builtin_amdgcn_mfma_f32_16x16x32_bf16(
                        a[mt], bf[nt], acc[mt][nt], 0, 0, 0);
        }
    }

    // ---- epilogue: relu + planar fp32 store
    int gx = tx0 + n16;
#pragma unroll
    for (int nt = 0; nt < 4; ++nt) {
        int gy = ty0 + 4 * wv + nt;
#pragma unroll
        for (int mt = 0; mt < 4; ++mt) {
#pragma unroll
            for (int r = 0; r < 4; ++r) {
                int oc = mt * 16 + quad * 4 + r;
                out[((size_t)b * out_ctot + oc) * HP + (size_t)gy * 128 + gx] =
                    fmaxf(acc[mt][nt][r], 0.0f);
            }
        }
    }
}

// ----------------------------------------------------- 1x1 conv, 64 out ch
template <int IC, bool RELU>
__global__ __launch_bounds__(256) void k_conv1x1(const float* __restrict__ in,
                                                 const float* __restrict__ w,
                                                 float* __restrict__ out) {
    __shared__ float wl[IC * 16];
    int tid = threadIdx.x;
    int occ = blockIdx.y, b = blockIdx.z;
    for (int idx = tid; idx < IC * 16; idx += 256) {
        int o = idx & 15, ic = idx >> 4;
        wl[idx] = w[(occ * 16 + o) * IC + ic];
    }
    __syncthreads();
    int p = blockIdx.x * 256 + tid;
    const float* inp = in + (size_t)b * IC * HP + p;
    float acc[16] = {};
    for (int ic = 0; ic < IC; ++ic) {
        float xv = inp[(size_t)ic * HP];
#pragma unroll
        for (int o = 0; o < 16; ++o) acc[o] += xv * wl[ic * 16 + o];
    }
    float* op = out + ((size_t)b * 64 + occ * 16) * HP + p;
#pragma unroll
    for (int o = 0; o < 16; ++o) op[o * HP] = RELU ? fmaxf(acc[o], 0.0f) : acc[o];
}

// ------------------------------- depthwise 3x3 (V slice) fused with v*(1+filt)
__global__ __launch_bounds__(256) void k_dwconv_v(const float* __restrict__ t,
                                                  const float* __restrict__ wdw,
                                                  const float* __restrict__ filt,
                                                  float* __restrict__ v) {
    long long idx = (long long)blockIdx.x * 256 + threadIdx.x;
    if (idx >= S) return;
    int j = (int)(idx & 127);
    int i = (int)((idx >> 7) & 127);
    int c = (int)((idx >> 14) & 63);
    long long bc = idx >> 14;
    const float* tp = t + bc * HP;
    const float* wp = wdw + c * 9;
    float acc = 0.0f;
#pragma unroll
    for (int ky = 0; ky < 3; ++ky) {
        int y = i + ky - 1;
        if (y < 0 || y >= 128) continue;
#pragma unroll
        for (int kx = 0; kx < 3; ++kx) {
            int x = j + kx - 1;
            if (x < 0 || x >= 128) continue;
            acc += tp[y * 128 + x] * wp[ky * 3 + kx];
        }
    }
    float f = filt[idx];
    v[idx] = acc * (1.0f + f);
}

// ---------------------------------------------------- window attention (8x8)
__global__ __launch_bounds__(256) void k_attn(const float* __restrict__ ll,
                                              const float* __restrict__ v,
                                              const float* __restrict__ table,
                                              const float* __restrict__ temp,
                                              float* __restrict__ outbuf) {
    __shared__ float qs[64][64];
    __shared__ float vs[64][64];
    __shared__ float inv[4][64];
    __shared__ float tb[225 * 4];
    int blk = blockIdx.x;
    int wj = blk & 15, wi = (blk >> 4) & 15, b = blk >> 8;
    int tid = threadIdx.x;

    for (int idx = tid; idx < 900; idx += 256) tb[idx] = table[idx];
    for (int idx = tid; idx < 4096; idx += 256) {
        int c = idx >> 6, n = idx & 63;
        int i = n >> 3, j = n & 7;
        int qy = (wi * 8 + i + 4) & 127, qx = (wj * 8 + j + 4) & 127;
        int vy = wi * 8 + i, vx = wj * 8 + j;
        size_t cb = ((size_t)b * 64 + c) * HP;
        qs[c][n] = ll[cb + qy * 128 + qx];
        vs[c][n] = v[cb + vy * 128 + vx];
    }
    __syncthreads();

    int h = tid >> 6, n = tid & 63;
    float q[16];
    float ss = 0.0f;
#pragma unroll
    for (int d = 0; d < 16; ++d) {
        q[d] = qs[h * 16 + d][n];
        ss += q[d] * q[d];
    }
    float invn = 1.0f / fmaxf(sqrtf(ss), 1e-12f);
    inv[h][n] = invn;
    __syncthreads();

    int i1 = n >> 3, j1 = n & 7;
    float tscale = temp[h];
    float p[64];
    float mx = -1e30f;
#pragma unroll
    for (int m = 0; m < 64; ++m) {
        float s = 0.0f;
#pragma unroll
        for (int d = 0; d < 16; ++d) s += q[d] * qs[h * 16 + d][m];
        s = s * invn * inv[h][m];
        int i2 = m >> 3, j2 = m & 7;
        s += tb[((i1 - i2 + 7) * 15 + (j1 - j2 + 7)) * 4 + h];
        s *= tscale;
        p[m] = s;
        mx = fmaxf(mx, s);
    }
    float sum = 0.0f;
#pragma unroll
    for (int m = 0; m < 64; ++m) {
        p[m] = __expf(p[m] - mx);
        sum += p[m];
    }
    float rs = 1.0f / sum;
    float acc[16] = {};
#pragma unroll
    for (int m = 0; m < 64; ++m) {
        float pm = p[m] * rs;
#pragma unroll
        for (int d = 0; d < 16; ++d) acc[d] += pm * vs[h * 16 + d][m];
    }
    int oy = (wi * 8 + i1 + 4) & 127, ox = (wj * 8 + j1 + 4) & 127;
#pragma unroll
    for (int d = 0; d < 16; ++d)
        outbuf[((size_t)b * 64 + h * 16 + d) * HP + oy * 128 + ox] = acc[d];
}

// ---------------------------------------------------------------- IDWT (Haar)
__global__ __launch_bounds__(256) void k_idwt(const float* __restrict__ ll, const float* __restrict__ lh,
                                              const float* __restrict__ hl, const float* __restrict__ hh,
                                              float* __restrict__ out) {
    long long idx = (long long)blockIdx.x * 256 + threadIdx.x;
    if (idx >= S) return;
    int j = (int)(idx & 127);
    int i = (int)((idx >> 7) & 127);
    long long bc = idx >> 14;
    float L = ll[idx], A = lh[idx], B = hl[idx], D = hh[idx];
    float a = (L + A + B + D) * 0.5f;
    float b = (L - A + B - D) * 0.5f;
    float c = (L + A - B - D) * 0.5f;
    float d = (L - A - B + D) * 0.5f;
    float* op = out + bc * 256 * 256;
    *(float2*)(op + (2 * i) * 256 + 2 * j) = make_float2(a, b);
    *(float2*)(op + (2 * i + 1) * 256 + 2 * j) = make_float2(c, d);
}

extern "C" void kernel_launch(void* const* d_in, const int* in_sizes, int n_in,
                              void* d_out, int out_size, void* d_ws, size_t ws_size,
                              hipStream_t stream) {
    const float* x        = (const float*)d_in[0];
    const float* temp     = (const float*)d_in[1];
    const float* table    = (const float*)d_in[2];
    const float* w_high1  = (const float*)d_in[3];  // (128,64,3,3)
    const float* w_high2  = (const float*)d_in[4];  // (64,128,1,1)
    const float* w_highout= (const float*)d_in[5];  // (192,64,3,3)
    const float* w_qkv    = (const float*)d_in[6];  // (192,64,1,1)
    const float* w_dwconv = (const float*)d_in[7];  // (192,1,3,3)
    const float* w_proj   = (const float*)d_in[8];  // (64,64,1,1)
    float* out = (float*)d_out;

    float* ws = (float*)d_ws;
    // 9 slots of S floats, lifetime-reused (same footprint as round 1):
    float* s0 = ws + 0 * S;  // ll (planar fp32)
    float* s1 = ws + 1 * S;  // lh planar -> filt1 ch0..63 -> lh2
    float* s2 = ws + 2 * S;  // hl planar -> filt1 ch64..127 -> hl2
    float* s3 = ws + 3 * S;  // hh planar -> hh2
    float* s4 = ws + 4 * S;  // T_lh (bf16) | T_hl (bf16)
    float* s5 = ws + 5 * S;  // T_hh (bf16) | reordered weights (bf16)
    float* s6 = ws + 6 * S;  // filt -> v
    float* s7 = ws + 7 * S;  // t -> attnout
    float* s8 = ws + 8 * S;  // proj out (ll-path into IDWT)

    unsigned short* T_lh = (unsigned short*)s4;
    unsigned short* T_hl = (unsigned short*)s4 + S;
    unsigned short* T_hh = (unsigned short*)s5;
    unsigned short* w_r1 = (unsigned short*)s5 + S;       // 128*576 bf16
    unsigned short* w_r2 = w_r1 + 128 * 576;              // 192*576 bf16

    const int nblk = (int)(S / 256);
    dim3 b256(256);

    // 1. DWT (planar fp32 subbands)
    k_dwt<<<nblk, b256, 0, stream>>>(x, s0, s1, s2, s3);

    // 2. NHWC bf16 transposes of lh/hl/hh + weight reorders
    dim3 tg(HP / 64, 8);
    k_to_nhwc<<<tg, b256, 0, stream>>>(s1, T_lh);
    k_to_nhwc<<<tg, b256, 0, stream>>>(s2, T_hl);
    k_to_nhwc<<<tg, b256, 0, stream>>>(s3, T_hh);
    k_wreorder<<<(128 * 576 + 255) / 256, b256, 0, stream>>>(w_high1, w_r1, 128 * 576);
    k_wreorder<<<(192 * 576 + 255) / 256, b256, 0, stream>>>(w_highout, w_r2, 192 * 576);

    // 3. filt1 = relu(conv3x3 g=2 on [lh,hl]) -> 128ch planar in s1..s2
    dim3 cg(64, 8);
    k_conv3x3_mfma<<<cg, b256, 0, stream>>>(T_lh, w_r1,            s1,            128);
    k_conv3x3_mfma<<<cg, b256, 0, stream>>>(T_hl, w_r1 + 64 * 576, s1 + 64 * HP,  128);

    // 4. filt = relu(1x1 128->64) -> s6
    dim3 g1(64, 4, 8);
    k_conv1x1<128, true><<<g1, b256, 0, stream>>>(s1, w_high2, s6);

    // 5. t = 1x1 conv of ll with V-rows of w_qkv -> s7
    k_conv1x1<64, false><<<g1, b256, 0, stream>>>(s0, w_qkv + 128 * 64, s7);

    // 6. v = dwconv3x3(t) * (1 + filt) -> s6 (in-place over filt)
    k_dwconv_v<<<nblk, b256, 0, stream>>>(s7, w_dwconv + 128 * 9, s6, s6);

    // 7. window attention -> s7
    k_attn<<<2048, b256, 0, stream>>>(s0, s6, table, temp, s7);

    // 8. proj 1x1 -> s8
    k_conv1x1<64, false><<<g1, b256, 0, stream>>>(s7, w_proj, s8);

    // 9. high-frequency output branch: 3 grouped conv3x3 + relu
    k_conv3x3_mfma<<<cg, b256, 0, stream>>>(T_lh, w_r2,             s1, 64);
    k_conv3x3_mfma<<<cg, b256, 0, stream>>>(T_hl, w_r2 + 64 * 576,  s2, 64);
    k_conv3x3_mfma<<<cg, b256, 0, stream>>>(T_hh, w_r2 + 128 * 576, s3, 64);

    // 10. IDWT -> out
    k_idwt<<<nblk, b256, 0, stream>>>(s8, s1, s2, s3, out);
}